// Round 10
// baseline (397.680 us; speedup 1.0000x reference)
//
#include <hip/hip_runtime.h>
#include <hip/hip_bf16.h>

// Problem constants (fixed by the reference)
#define N_B   4
#define T_S   2048
#define DM    1024
#define HEADS 16
#define DK    64

typedef unsigned short ubf16;  // raw bf16 bits
typedef __attribute__((ext_vector_type(8))) short short8;     // MFMA A/B frag (8 bf16)
typedef __attribute__((ext_vector_type(4))) float floatx4;    // 16x16 MFMA C/D frag
typedef __attribute__((ext_vector_type(16))) float floatx16;  // 32x32 MFMA C/D frag
typedef __attribute__((ext_vector_type(4))) unsigned uintx4;

__device__ __forceinline__ unsigned short f2bf(float f) {
    unsigned u = __float_as_uint(f);
    u += 0x7fff + ((u >> 16) & 1);   // round-to-nearest-even
    return (unsigned short)(u >> 16);
}
// packed f32x2 -> bf16x2 via HW cvt_pk (r3/r5/r7-proven in P-path and staging)
__device__ __forceinline__ unsigned cvtpk(float a, float b) {
    unsigned r;
    asm("v_cvt_pk_bf16_f32 %0, %1, %2" : "=v"(r) : "v"(a), "v"(b));
    return r;
}
// swap a.hi32lanes <-> b.lo32lanes (gfx950)
__device__ __forceinline__ void pswap(unsigned& a, unsigned& b) {
    asm volatile("v_permlane32_swap_b32 %0, %1" : "+v"(a), "+v"(b));
}

// async global->LDS DMA, 16 B per lane; LDS dest = wave-uniform base + lane*16
__device__ __forceinline__ void async_copy16(const ubf16* g, ubf16* l) {
    __builtin_amdgcn_global_load_lds(
        (const __attribute__((address_space(1))) void*)g,
        (__attribute__((address_space(3))) void*)l, 16, 0, 0);
}

// ---------------------------------------------------------------------------
// Weight transpose+convert, all 4 weights in ONE launch (z picks tensor):
// W fp32 [k][n] -> Wt bf16 [n][k].
// ---------------------------------------------------------------------------
__global__ __launch_bounds__(256) void wtrans4(
    const float* __restrict__ W0, const float* __restrict__ W1,
    const float* __restrict__ W2, const float* __restrict__ W3,
    ubf16* __restrict__ Y0, ubf16* __restrict__ Y1,
    ubf16* __restrict__ Y2, ubf16* __restrict__ Y3)
{
    const int z = blockIdx.z;
    const float* W = z == 0 ? W0 : (z == 1 ? W1 : (z == 2 ? W2 : W3));
    ubf16* Wt      = z == 0 ? Y0 : (z == 1 ? Y1 : (z == 2 ? Y2 : Y3));

    __shared__ ubf16 T[64][72];
    const int tid = threadIdx.x;
    const int kb = blockIdx.x * 64, nb = blockIdx.y * 64;
    const int r = tid >> 2, cc = (tid & 3) * 16;
    const float* p = W + (size_t)(kb + r) * 1024 + nb + cc;
#pragma unroll
    for (int t = 0; t < 16; t += 4) {
        float4 x = *(const float4*)(p + t);
        T[r][cc + t + 0] = f2bf(x.x);
        T[r][cc + t + 1] = f2bf(x.y);
        T[r][cc + t + 2] = f2bf(x.z);
        T[r][cc + t + 3] = f2bf(x.w);
    }
    __syncthreads();
    ubf16 buf[16];
#pragma unroll
    for (int t = 0; t < 16; ++t) buf[t] = T[cc + t][r];   // transpose read
    ubf16* op = Wt + (size_t)(nb + r) * 1024 + kb + cc;
    *(uint4*)op       = *(uint4*)buf;
    *(uint4*)(op + 8) = *(uint4*)(buf + 8);
}

// ---------------------------------------------------------------------------
// Fused Q/K/V projection GEMM (r7/r9 version, measured 123-128 us): grid z
// picks (X, Wt, bias, Y, epilogue).  1536 blocks -> ~6/CU queued, amortizes
// the per-block latency path.  A = fp32 X reg-staged; B = bf16 Wt via
// global_load_lds.  Tile 128x128, BK=64, 4 waves; As single-buffered
// (48 KiB -> 3 blocks/CU).  XOR-swizzled LDS.
// z<2 -> heads [n][h][t][d]; z==2 -> V-transposed [n][h][d][t].
// ---------------------------------------------------------------------------
__global__ __launch_bounds__(256) void proj_mfma(
    const float* __restrict__ Xq, const float* __restrict__ Xk,
    const float* __restrict__ Xv,
    const ubf16* __restrict__ WQ, const ubf16* __restrict__ WK,
    const ubf16* __restrict__ WV,
    const float* __restrict__ bQ, const float* __restrict__ bK,
    const float* __restrict__ bV,
    ubf16* __restrict__ YQ, ubf16* __restrict__ YK, ubf16* __restrict__ YV)
{
    __shared__ ubf16 As[128][64];     // 16 KiB, single buffer
    __shared__ ubf16 Bs[2][128][64];  // 16 KiB per buf

    const int z = blockIdx.z;
    const float* X    = z == 0 ? Xq : (z == 1 ? Xk : Xv);
    const ubf16* Wt   = z == 0 ? WQ : (z == 1 ? WK : WV);
    const float* bias = z == 0 ? bQ : (z == 1 ? bK : bV);
    ubf16* Y          = z == 0 ? YQ : (z == 1 ? YK : YV);

    const int tid = threadIdx.x;
    const int mb = blockIdx.x * 128, nb = blockIdx.y * 128;
    const int w = tid >> 6, lid = tid & 63, quad = lid >> 4, l15 = lid & 15;
    const int wr = (w >> 1) * 64, wc = (w & 1) * 64;

    // B DMA pattern: row = c*8 + (lid>>3), source chunk pre-inverse-swizzled
    const int srow = lid >> 3;                 // 0..7
    const int sch  = (lid & 7) ^ srow;
    const ubf16* gB = Wt + (size_t)(nb + w * 32 + srow) * 1024 + sch * 8;

    // A reg-staging pattern: lane owns row c*8+arow, fp32 chunk ach (8 floats)
    const int arow = lid >> 3, ach = lid & 7;
    const int aslot = ach ^ arow;              // swizzled LDS chunk for write
    const float* gA = X + (size_t)(mb + w * 32 + arow) * 1024 + ach * 8;

    // frag-read swizzled chunk offsets: ((ks*4+quad) ^ (row&7)) * 8
    const int m7 = l15 & 7;
    const int sw0 = ((0 + quad) ^ m7) * 8;     // ks = 0
    const int sw1 = ((4 + quad) ^ m7) * 8;     // ks = 1

    floatx4 acc[4][4] = {};
    float4 ra[8];

#define PROJ_STAGEB(KB, BUF)                                                  \
    {                                                                         \
        _Pragma("unroll")                                                     \
        for (int c = 0; c < 4; ++c)                                           \
            async_copy16(gB + (size_t)(c * 8) * 1024 + (KB),                  \
                         &Bs[BUF][w * 32 + c * 8][0]);                        \
    }
#define PROJ_LOADA(KB)                                                        \
    {                                                                         \
        _Pragma("unroll")                                                     \
        for (int c = 0; c < 4; ++c) {                                         \
            const float* p = gA + (size_t)(c * 8) * 1024 + (KB);              \
            ra[2 * c]     = *(const float4*)p;                                \
            ra[2 * c + 1] = *(const float4*)(p + 4);                          \
        }                                                                     \
    }
#define PROJ_WRITEA()                                                         \
    {                                                                         \
        _Pragma("unroll")                                                     \
        for (int c = 0; c < 4; ++c) {                                         \
            uintx4 pk;                                                        \
            pk[0] = cvtpk(ra[2 * c][0], ra[2 * c][1]);                        \
            pk[1] = cvtpk(ra[2 * c][2], ra[2 * c][3]);                        \
            pk[2] = cvtpk(ra[2 * c + 1][0], ra[2 * c + 1][1]);                \
            pk[3] = cvtpk(ra[2 * c + 1][2], ra[2 * c + 1][3]);                \
            *(uintx4*)(&As[w * 32 + c * 8 + arow][aslot * 8]) = pk;           \
        }                                                                     \
    }

    // prologue: tile 0
    PROJ_STAGEB(0, 0);
    PROJ_LOADA(0);
    PROJ_WRITEA();
    __syncthreads();   // implicit vmcnt/lgkm drain: tile 0 resident

    for (int t = 0; t < 16; ++t) {
        const int cur = t & 1;
        if (t < 15) {
            PROJ_LOADA((t + 1) * 64);             // A loads issued early (T14)
            PROJ_STAGEB((t + 1) * 64, cur ^ 1);   // B DMA for next tile
        }

#pragma unroll
        for (int ks = 0; ks < 2; ++ks) {
            const int sw = ks ? sw1 : sw0;
            short8 af[4], bf[4];
#pragma unroll
            for (int i = 0; i < 4; ++i)
                af[i] = *(const short8*)(&As[wr + i * 16 + l15][0] + sw);
#pragma unroll
            for (int j = 0; j < 4; ++j)
                bf[j] = *(const short8*)(&Bs[cur][wc + j * 16 + l15][0] + sw);
#pragma unroll
            for (int i = 0; i < 4; ++i)
#pragma unroll
                for (int j = 0; j < 4; ++j)
                    acc[i][j] = __builtin_amdgcn_mfma_f32_16x16x32_bf16(
                        af[i], bf[j], acc[i][j], 0, 0, 0);
        }

        if (t < 15) {
            __syncthreads();   // As reads done everywhere; B DMA + A loads landed
            PROJ_WRITEA();     // overwrite As with tile t+1
            __syncthreads();   // As writes visible to all waves
        }
    }
#undef PROJ_STAGEB
#undef PROJ_LOADA
#undef PROJ_WRITEA

    // epilogue
#pragma unroll
    for (int j = 0; j < 4; ++j) {
        const int c = nb + wc + j * 16 + l15;
        const float bx = bias[c];
        const int hh = c >> 6, d = c & 63;
#pragma unroll
        for (int i = 0; i < 4; ++i) {
            if (z < 2) {   // heads [n][h][t][d]
#pragma unroll
                for (int r = 0; r < 4; ++r) {
                    const int m = mb + wr + i * 16 + quad * 4 + r;
                    const int nn = m >> 11, tt = m & 2047;
                    Y[(((size_t)(nn * HEADS + hh)) * T_S + tt) * DK + d] =
                        f2bf(acc[i][j][r] + bx);
                }
            } else {       // V transposed [n][h][d][t]
                const int m0 = mb + wr + i * 16 + quad * 4;
                const int nn = m0 >> 11, t0 = m0 & 2047;
                ushort4 o;
                o.x = f2bf(acc[i][j][0] + bx);
                o.y = f2bf(acc[i][j][1] + bx);
                o.z = f2bf(acc[i][j][2] + bx);
                o.w = f2bf(acc[i][j][3] + bx);
                *(ushort4*)(Y + (((size_t)(nn * HEADS + hh)) * DK + d) * T_S + t0) = o;
            }
        }
    }
}

// ---------------------------------------------------------------------------
// Output-projection GEMM, round-10: tile 128x64 -> grid (64,16) = 1024
// blocks (was 512 at 128x128).  Mechanism (validated r8 split-proj, and by
// r7==r9 equality): 512-block launches are a single no-backfill generation
// whose duration collapses to the per-block latency path (~125us, 137 TF).
// 1024 blocks = 4 resident/CU (LDS 32 KiB: As 16 + Bs 2x8) cross-cover the
// barrier drains, and the per-block path shrinks ~35% (16 MFMA/iter, half
// the B-DMA).  A = bf16 reg-staged; B via global_load_lds; XOR-swizzle.
// Wave tile 64x32 (2x2 waves).  Output fp32 row-major [m][1024].
// ---------------------------------------------------------------------------
__global__ __launch_bounds__(256) void gemmo_mfma(
    const ubf16* __restrict__ X, const ubf16* __restrict__ Wt,
    const float* __restrict__ bias, float* __restrict__ Y)
{
    __shared__ ubf16 As[128][64];     // 16 KiB, single buffer
    __shared__ ubf16 Bs[2][64][64];   // 8 KiB per buf

    const int tid = threadIdx.x;
    const int mb = blockIdx.x * 128, nb = blockIdx.y * 64;
    const int w = tid >> 6, lid = tid & 63, quad = lid >> 4, l15 = lid & 15;
    const int wr = (w >> 1) * 64, wc = (w & 1) * 32;

    const int srow = lid >> 3;                 // 0..7
    const int sch  = (lid & 7) ^ srow;
    // B: wave w stages rows w*16 + cc*8 + srow (cc = 0..1); row&7 == srow
    const ubf16* gB = Wt + (size_t)(nb + w * 16 + srow) * 1024 + sch * 8;

    // A reg-staging: lane owns rows w*32 + c*8 + arow, bf16 chunk ach (16 B)
    const int arow = lid >> 3, ach = lid & 7;
    const int aslot = ach ^ arow;
    const ubf16* gA = X + (size_t)(mb + w * 32 + arow) * 1024 + ach * 8;

    const int m7 = l15 & 7;
    const int sw0 = ((0 + quad) ^ m7) * 8;
    const int sw1 = ((4 + quad) ^ m7) * 8;

    floatx4 acc[4][2] = {};
    uint4 ra[4];

#define GO_STAGEB(KB, BUF)                                                    \
    {                                                                         \
        _Pragma("unroll")                                                     \
        for (int cc = 0; cc < 2; ++cc)                                        \
            async_copy16(gB + (size_t)(cc * 8) * 1024 + (KB),                 \
                         &Bs[BUF][w * 16 + cc * 8][0]);                       \
    }
#define GO_LOADA(KB)                                                          \
    {                                                                         \
        _Pragma("unroll")                                                     \
        for (int c = 0; c < 4; ++c)                                           \
            ra[c] = *(const uint4*)(gA + (size_t)(c * 8) * 1024 + (KB));      \
    }
#define GO_WRITEA()                                                           \
    {                                                                         \
        _Pragma("unroll")                                                     \
        for (int c = 0; c < 4; ++c)                                           \
            *(uint4*)(&As[w * 32 + c * 8 + arow][aslot * 8]) = ra[c];         \
    }

    GO_STAGEB(0, 0);
    GO_LOADA(0);
    GO_WRITEA();
    __syncthreads();

    for (int t = 0; t < 16; ++t) {
        const int cur = t & 1;
        if (t < 15) {
            GO_LOADA((t + 1) * 64);
            GO_STAGEB((t + 1) * 64, cur ^ 1);
        }

#pragma unroll
        for (int ks = 0; ks < 2; ++ks) {
            const int sw = ks ? sw1 : sw0;
            short8 af[4], bf[2];
#pragma unroll
            for (int i = 0; i < 4; ++i)
                af[i] = *(const short8*)(&As[wr + i * 16 + l15][0] + sw);
#pragma unroll
            for (int j = 0; j < 2; ++j)
                bf[j] = *(const short8*)(&Bs[cur][wc + j * 16 + l15][0] + sw);
#pragma unroll
            for (int i = 0; i < 4; ++i)
#pragma unroll
                for (int j = 0; j < 2; ++j)
                    acc[i][j] = __builtin_amdgcn_mfma_f32_16x16x32_bf16(
                        af[i], bf[j], acc[i][j], 0, 0, 0);
        }

        if (t < 15) {
            __syncthreads();
            GO_WRITEA();
            __syncthreads();
        }
    }
#undef GO_STAGEB
#undef GO_LOADA
#undef GO_WRITEA

#pragma unroll
    for (int j = 0; j < 2; ++j) {
        const int c = nb + wc + j * 16 + l15;
        const float bx = bias[c];
#pragma unroll
        for (int i = 0; i < 4; ++i) {
#pragma unroll
            for (int r = 0; r < 4; ++r) {
                const int m = mb + wr + i * 16 + quad * 4 + r;
                Y[(size_t)m * DM + c] = acc[i][j][r] + bx;
            }
        }
    }
}

// ---------------------------------------------------------------------------
// Flash attention — BYTE-IDENTICAL to r3/r7/r8/r9 (measured 81.3-82.6 us).
// 32x32x16 MFMA, swapped operands, in-register P, LDS double-buffered K/V
// via global_load_lds, XOR-swizzled.  Causal balance: block bx does q-tile
// (15-bx) then bx; grid (8, HEADS, N_B).
// ---------------------------------------------------------------------------
__global__ __launch_bounds__(256, 4) void attn_mfma(
    const ubf16* __restrict__ Qh, const ubf16* __restrict__ Kh,
    const ubf16* __restrict__ Vt, const int* __restrict__ pm,
    ubf16* __restrict__ A)
{
    __shared__ ubf16 Ks[2][64 * 64];   // 8 KiB x2
    __shared__ ubf16 Vs[2][64 * 64];   // 8 KiB x2

    const int tid = threadIdx.x;
    const int w = tid >> 6, lid = tid & 63;
    const int l31 = lid & 31, hi = lid >> 5;
    const int bx = (int)blockIdx.x;                 // 0..7
    const int h = blockIdx.y, n = blockIdx.z;
    const size_t qkbase = ((size_t)(n * HEADS + h)) * T_S * DK;
    const size_t vbase  = ((size_t)(n * HEADS + h)) * DK * T_S;
    const int* pmn = pm + (size_t)n * T_S;

    const int srow = lid >> 3;                    // + c*8
    const int sch  = (lid & 7) ^ (srow & 7);      // pre-inverse-swizzled chunk

    int sw[4];
#pragma unroll
    for (int j = 0; j < 4; ++j) sw[j] = (((hi + 2 * j) ^ (l31 & 7)) * 8);

    for (int pass = 0; pass < 2; ++pass) {
        const int qt = pass == 0 ? (15 - bx) : bx;   // big pass first
        const int qb = qt * 128 + w * 32;            // this wave's q base
        const int qrow = qb + l31;                   // this lane's q

        short8 qf[4];
        {
            const ubf16* qp = Qh + qkbase + (size_t)qrow * DK + hi * 8;
#pragma unroll
            for (int dk = 0; dk < 4; ++dk)
                qf[dk] = *(const short8*)(qp + dk * 16);
        }

        const int ktm = 2 * qt + 1;            // block-uniform last tile

        {
            const int c0 = 2 * w;
#pragma unroll
            for (int cc = 0; cc < 2; ++cc) {
                const int c = c0 + cc;
                const int row = c * 8 + srow;
                async_copy16(Kh + qkbase + (size_t)row * DK + sch * 8, &Ks[0][c * 512]);
                async_copy16(Vt + vbase + (size_t)row * T_S + sch * 8, &Vs[0][c * 512]);
            }
        }
        __syncthreads();   // implicit vmcnt(0): tile 0 resident

        floatx16 o0 = {}, o1 = {};   // O^T: d = dc*32+(r&3)+8*(r>>2)+4*hi, q=l31
        float lsum = 0.f;

        for (int kt = 0; kt <= ktm; ++kt) {
            const int cur = kt & 1;
            const int kb = kt * 64;

            if (kt < ktm) {
                const int kb2 = kb + 64;
                const int c0 = 2 * w;
#pragma unroll
                for (int cc = 0; cc < 2; ++cc) {
                    const int c = c0 + cc;
                    const int row = c * 8 + srow;
                    async_copy16(Kh + qkbase + (size_t)(kb2 + row) * DK + sch * 8,
                                 &Ks[cur ^ 1][c * 512]);
                    async_copy16(Vt + vbase + (size_t)row * T_S + kb2 + sch * 8,
                                 &Vs[cur ^ 1][c * 512]);
                }
            }

            if (kb <= qb + 31) {   // wave-uniform: tile has visible keys
                const unsigned long long pmask = __ballot(pmn[kb + lid] != 0);
                const ubf16* Kr0 = &Ks[cur][l31 * 64];
                const ubf16* Kr1 = Kr0 + 32 * 64;
                const ubf16* Vr0 = &Vs[cur][l31 * 64];
                const ubf16* Vr1 = Vr0 + 32 * 64;
                const int qrel = qrow - kb;

                // ---------- half A: keys kb .. kb+31 ----------
                {
                    floatx16 s = {};
#pragma unroll
                    for (int dk = 0; dk < 4; ++dk) {
                        short8 kf = *(const short8*)(Kr0 + sw[dk]);
                        s = __builtin_amdgcn_mfma_f32_32x32x16_bf16(kf, qf[dk], s, 0, 0, 0);
                    }
                    float p[16];
                    const bool full = (kb + 31 <= qb) &&
                                      ((unsigned)pmask == 0xffffffffu);
                    if (full) {
#pragma unroll
                        for (int r = 0; r < 16; ++r) {
                            p[r] = __expf(s[r] * 0.125f);
                            lsum += p[r];
                        }
                    } else {
#pragma unroll
                        for (int r = 0; r < 16; ++r) {
                            const int k0 = (r & 3) + 8 * (r >> 2) + 4 * hi;
                            const bool ok = (((pmask >> k0) & 1ull) != 0) && (k0 <= qrel);
                            p[r] = ok ? __expf(s[r] * 0.125f) : 0.f;
                            lsum += p[r];
                        }
                    }
                    unsigned wa[8];
#pragma unroll
                    for (int t = 0; t < 8; ++t) wa[t] = cvtpk(p[2 * t], p[2 * t + 1]);
                    pswap(wa[0], wa[2]); pswap(wa[1], wa[3]);
                    pswap(wa[4], wa[6]); pswap(wa[5], wa[7]);
                    short8 pf0 = __builtin_bit_cast(short8, (uintx4){wa[0], wa[1], wa[2], wa[3]});
                    short8 pf1 = __builtin_bit_cast(short8, (uintx4){wa[4], wa[5], wa[6], wa[7]});
                    {
                        short8 vf0 = *(const short8*)(Vr0 + sw[0]);
                        short8 vf1 = *(const short8*)(Vr1 + sw[0]);
                        o0 = __builtin_amdgcn_mfma_f32_32x32x16_bf16(vf0, pf0, o0, 0, 0, 0);
                        o1 = __builtin_amdgcn_mfma_f32_32x32x16_bf16(vf1, pf0, o1, 0, 0, 0);
                        vf0 = *(const short8*)(Vr0 + sw[1]);
                        vf1 = *(const short8*)(Vr1 + sw[1]);
                        o0 = __builtin_amdgcn_mfma_f32_32x32x16_bf16(vf0, pf1, o0, 0, 0, 0);
                        o1 = __builtin_amdgcn_mfma_f32_32x32x16_bf16(vf1, pf1, o1, 0, 0, 0);
                    }
                }

                // ---------- half B: keys kb+32 .. kb+63 ----------
                if (kb + 32 <= qb + 31) {
                    floatx16 s = {};
#pragma unroll
                    for (int dk = 0; dk < 4; ++dk) {
                        short8 kf = *(const short8*)(Kr1 + sw[dk]);
                        s = __builtin_amdgcn_mfma_f32_32x32x16_bf16(kf, qf[dk], s, 0, 0, 0);
                    }
                    float p[16];
                    const bool full = (kb + 63 <= qb) &&
                                      ((unsigned)(pmask >> 32) == 0xffffffffu);
                    if (full) {
#pragma unroll
                        for (int r = 0; r < 16; ++r) {
                            p[r] = __expf(s[r] * 0.125f);
                            lsum += p[r];
                        }
                    } else {
#pragma unroll
                        for (int r = 0; r < 16; ++r) {
                            const int k1 = 32 + (r & 3) + 8 * (r >> 2) + 4 * hi;
                            const bool ok = (((pmask >> k1) & 1ull) != 0) && (k1 <= qrel);
                            p[r] = ok ? __expf(s[r] * 0.125f) : 0.f;
                            lsum += p[r];
                        }
                    }
                    unsigned wb[8];
#pragma unroll
                    for (int t = 0; t < 8; ++t) wb[t] = cvtpk(p[2 * t], p[2 * t + 1]);
                    pswap(wb[0], wb[2]); pswap(wb[1], wb[3]);
                    pswap(wb[4], wb[6]); pswap(wb[5], wb[7]);
                    short8 pf2 = __builtin_bit_cast(short8, (uintx4){wb[0], wb[1], wb[2], wb[3]});
                    short8 pf3 = __builtin_bit_cast(short8, (uintx4){wb[4], wb[5], wb[6], wb[7]});
                    {
                        short8 vf0 = *(const short8*)(Vr0 + sw[2]);
                        short8 vf1 = *(const short8*)(Vr1 + sw[2]);
                        o0 = __builtin_amdgcn_mfma_f32_32x32x16_bf16(vf0, pf2, o0, 0, 0, 0);
                        o1 = __builtin_amdgcn_mfma_f32_32x32x16_bf16(vf1, pf2, o1, 0, 0, 0);
                        vf0 = *(const short8*)(Vr0 + sw[3]);
                        vf1 = *(const short8*)(Vr1 + sw[3]);
                        o0 = __builtin_amdgcn_mfma_f32_32x32x16_bf16(vf0, pf3, o0, 0, 0, 0);
                        o1 = __builtin_amdgcn_mfma_f32_32x32x16_bf16(vf1, pf3, o1, 0, 0, 0);
                    }
                }
            }
            __syncthreads();   // cur reads done; next-tile DMA drained
        }

        // ---- normalize + store: A [n][t][h*64+d] bf16 ----
        lsum += __shfl_xor(lsum, 32);
        const float inv = lsum > 0.f ? 1.0f / lsum : 0.f;

        ubf16* ap = A + ((size_t)n * T_S + qrow) * DM + h * DK;
#pragma unroll
        for (int g = 0; g < 4; ++g) {
            uint2 uv;
            uv.x = cvtpk(o0[4 * g + 0] * inv, o0[4 * g + 1] * inv);
            uv.y = cvtpk(o0[4 * g + 2] * inv, o0[4 * g + 3] * inv);
            *(uint2*)(ap + 8 * g + 4 * hi) = uv;
            uv.x = cvtpk(o1[4 * g + 0] * inv, o1[4 * g + 1] * inv);
            uv.y = cvtpk(o1[4 * g + 2] * inv, o1[4 * g + 3] * inv);
            *(uint2*)(ap + 32 + 8 * g + 4 * hi) = uv;
        }
    }
}

// ---------------------------------------------------------------------------
extern "C" void kernel_launch(void* const* d_in, const int* in_sizes, int n_in,
                              void* d_out, int out_size, void* d_ws, size_t ws_size,
                              hipStream_t stream)
{
    const float* q  = (const float*)d_in[0];
    const float* k  = (const float*)d_in[1];
    const float* v  = (const float*)d_in[2];
    const int*   pm = (const int*)d_in[3];
    const float* Wq = (const float*)d_in[4];
    const float* bq = (const float*)d_in[5];
    const float* Wk = (const float*)d_in[6];
    const float* bk = (const float*)d_in[7];
    const float* Wv = (const float*)d_in[8];
    const float* bv = (const float*)d_in[9];
    const float* Wo = (const float*)d_in[10];
    const float* bo = (const float*)d_in[11];
    float* out = (float*)d_out;

    const size_t WT_E = (size_t)1024 * 1024;      // per-weight bf16 elems (2 MiB)
    const size_t HB_E = (size_t)8192 * 1024;      // batched per-tensor elems (16 MiB)
    const size_t PB_E = (size_t)2048 * 1024;      // per-batch elems (4 MiB)

    ubf16* WtQ = (ubf16*)d_ws;
    ubf16* WtK = WtQ + WT_E;
    ubf16* WtV = WtK + WT_E;
    ubf16* WtO = WtV + WT_E;
    ubf16* base = WtO + WT_E;

    dim3 blk(256);
    dim3 gtr(16, 16, 4);    // all four weight transposes in one launch
    wtrans4<<<gtr, blk, 0, stream>>>(Wq, Wk, Wv, Wo, WtQ, WtK, WtV, WtO);

    const size_t need_batched = (4 * WT_E + 4 * HB_E) * sizeof(ubf16);  // 72 MiB
    if (ws_size >= need_batched) {
        ubf16* Qh = base;
        ubf16* Kh = Qh + HB_E;
        ubf16* Vt = Kh + HB_E;
        ubf16* Aw = Vt + HB_E;
        dim3 gp(64, 8, 3);           // fused Q/K/V projections (1536 blocks)
        proj_mfma<<<gp, blk, 0, stream>>>(q, k, v, WtQ, WtK, WtV,
                                          bq, bk, bv, Qh, Kh, Vt);
        dim3 ga(8, HEADS, N_B);      // paired q-tiles (34 key-tiles per block)
        attn_mfma<<<ga, blk, 0, stream>>>(Qh, Kh, Vt, pm, Aw);
        dim3 gg(64, 16);             // 128x64 tiles -> 1024 blocks
        gemmo_mfma<<<gg, blk, 0, stream>>>(Aw, WtO, bo, out);
    } else {
        // per-batch fallback (24 MiB workspace)
        ubf16* Qh = base;
        ubf16* Kh = Qh + PB_E;
        ubf16* Vt = Kh + PB_E;
        ubf16* Aw = Vt + PB_E;
        dim3 gp(16, 8, 3);
        dim3 ga(8, HEADS, 1);
        dim3 gg(16, 16);
        for (int n = 0; n < N_B; ++n) {
            const size_t xoff = (size_t)n * T_S * DM;
            proj_mfma<<<gp, blk, 0, stream>>>(q + xoff, k + xoff, v + xoff,
                                              WtQ, WtK, WtV, bq, bk, bv,
                                              Qh, Kh, Vt);
            attn_mfma<<<ga, blk, 0, stream>>>(Qh, Kh, Vt, pm + n * T_S, Aw);
            gemmo_mfma<<<gg, blk, 0, stream>>>(Aw, WtO, bo, out + xoff);
        }
    }
}

// Round 11
// 351.758 us; speedup vs baseline: 1.1305x; 1.1305x over previous
//
#include <hip/hip_runtime.h>
#include <hip/hip_bf16.h>

// Problem constants (fixed by the reference)
#define N_B   4
#define T_S   2048
#define DM    1024
#define HEADS 16
#define DK    64

typedef unsigned short ubf16;  // raw bf16 bits
typedef __attribute__((ext_vector_type(8))) short short8;     // MFMA A/B frag (8 bf16)
typedef __attribute__((ext_vector_type(4))) float floatx4;    // 16x16 MFMA C/D frag
typedef __attribute__((ext_vector_type(16))) float floatx16;  // 32x32 MFMA C/D frag
typedef __attribute__((ext_vector_type(4))) unsigned uintx4;

__device__ __forceinline__ unsigned short f2bf(float f) {
    unsigned u = __float_as_uint(f);
    u += 0x7fff + ((u >> 16) & 1);   // round-to-nearest-even
    return (unsigned short)(u >> 16);
}
// packed f32x2 -> bf16x2 via HW cvt_pk (r3/r5/r7-proven in P-path and staging)
__device__ __forceinline__ unsigned cvtpk(float a, float b) {
    unsigned r;
    asm("v_cvt_pk_bf16_f32 %0, %1, %2" : "=v"(r) : "v"(a), "v"(b));
    return r;
}
// swap a.hi32lanes <-> b.lo32lanes (gfx950)
__device__ __forceinline__ void pswap(unsigned& a, unsigned& b) {
    asm volatile("v_permlane32_swap_b32 %0, %1" : "+v"(a), "+v"(b));
}

// async global->LDS DMA, 16 B per lane; LDS dest = wave-uniform base + lane*16
__device__ __forceinline__ void async_copy16(const ubf16* g, ubf16* l) {
    __builtin_amdgcn_global_load_lds(
        (const __attribute__((address_space(1))) void*)g,
        (__attribute__((address_space(3))) void*)l, 16, 0, 0);
}

// ---------------------------------------------------------------------------
// Weight transpose+convert: W fp32 [k][n] -> Wt bf16 [n][k].
// ---------------------------------------------------------------------------
__global__ __launch_bounds__(256) void wtrans(
    const float* __restrict__ W, ubf16* __restrict__ Wt)
{
    __shared__ ubf16 T[64][72];
    const int tid = threadIdx.x;
    const int kb = blockIdx.x * 64, nb = blockIdx.y * 64;
    const int r = tid >> 2, cc = (tid & 3) * 16;
    const float* p = W + (size_t)(kb + r) * 1024 + nb + cc;
#pragma unroll
    for (int t = 0; t < 16; t += 4) {
        float4 x = *(const float4*)(p + t);
        T[r][cc + t + 0] = f2bf(x.x);
        T[r][cc + t + 1] = f2bf(x.y);
        T[r][cc + t + 2] = f2bf(x.z);
        T[r][cc + t + 3] = f2bf(x.w);
    }
    __syncthreads();
    ubf16 buf[16];
#pragma unroll
    for (int t = 0; t < 16; ++t) buf[t] = T[cc + t][r];   // transpose read
    ubf16* op = Wt + (size_t)(nb + r) * 1024 + kb + cc;
    *(uint4*)op       = *(uint4*)buf;
    *(uint4*)(op + 8) = *(uint4*)(buf + 8);
}

// ---------------------------------------------------------------------------
// Fused Q/K/V projection GEMM (r7 version, measured 123.6 us): grid z picks
// (X, Wt, bias, Y, epilogue).  1536 blocks; A-panel-sharing blocks (same
// blockIdx.x, ids differing by 64 = 0 mod 8) land on the same XCD under the
// round-robin heuristic -> A fp32 re-reads are L2-local.  A = fp32 X
// reg-staged; B = bf16 Wt via global_load_lds.  Tile 128x128, BK=64,
// 4 waves; As single-buffered (48 KiB -> 3 blocks/CU).  XOR-swizzled LDS.
// z<2 -> heads [n][h][t][d]; z==2 -> V-transposed [n][h][d][t].
// ---------------------------------------------------------------------------
__global__ __launch_bounds__(256) void proj_mfma(
    const float* __restrict__ Xq, const float* __restrict__ Xk,
    const float* __restrict__ Xv,
    const ubf16* __restrict__ WQ, const ubf16* __restrict__ WK,
    const ubf16* __restrict__ WV,
    const float* __restrict__ bQ, const float* __restrict__ bK,
    const float* __restrict__ bV,
    ubf16* __restrict__ YQ, ubf16* __restrict__ YK, ubf16* __restrict__ YV)
{
    __shared__ ubf16 As[128][64];     // 16 KiB, single buffer
    __shared__ ubf16 Bs[2][128][64];  // 16 KiB per buf

    const int z = blockIdx.z;
    const float* X    = z == 0 ? Xq : (z == 1 ? Xk : Xv);
    const ubf16* Wt   = z == 0 ? WQ : (z == 1 ? WK : WV);
    const float* bias = z == 0 ? bQ : (z == 1 ? bK : bV);
    ubf16* Y          = z == 0 ? YQ : (z == 1 ? YK : YV);

    const int tid = threadIdx.x;
    const int mb = blockIdx.x * 128, nb = blockIdx.y * 128;
    const int w = tid >> 6, lid = tid & 63, quad = lid >> 4, l15 = lid & 15;
    const int wr = (w >> 1) * 64, wc = (w & 1) * 64;

    // B DMA pattern: row = c*8 + (lid>>3), source chunk pre-inverse-swizzled
    const int srow = lid >> 3;                 // 0..7
    const int sch  = (lid & 7) ^ srow;
    const ubf16* gB = Wt + (size_t)(nb + w * 32 + srow) * 1024 + sch * 8;

    // A reg-staging pattern: lane owns row c*8+arow, fp32 chunk ach (8 floats)
    const int arow = lid >> 3, ach = lid & 7;
    const int aslot = ach ^ arow;              // swizzled LDS chunk for write
    const float* gA = X + (size_t)(mb + w * 32 + arow) * 1024 + ach * 8;

    // frag-read swizzled chunk offsets: ((ks*4+quad) ^ (row&7)) * 8
    const int m7 = l15 & 7;
    const int sw0 = ((0 + quad) ^ m7) * 8;     // ks = 0
    const int sw1 = ((4 + quad) ^ m7) * 8;     // ks = 1

    floatx4 acc[4][4] = {};
    float4 ra[8];

#define PROJ_STAGEB(KB, BUF)                                                  \
    {                                                                         \
        _Pragma("unroll")                                                     \
        for (int c = 0; c < 4; ++c)                                           \
            async_copy16(gB + (size_t)(c * 8) * 1024 + (KB),                  \
                         &Bs[BUF][w * 32 + c * 8][0]);                        \
    }
#define PROJ_LOADA(KB)                                                        \
    {                                                                         \
        _Pragma("unroll")                                                     \
        for (int c = 0; c < 4; ++c) {                                         \
            const float* p = gA + (size_t)(c * 8) * 1024 + (KB);              \
            ra[2 * c]     = *(const float4*)p;                                \
            ra[2 * c + 1] = *(const float4*)(p + 4);                          \
        }                                                                     \
    }
#define PROJ_WRITEA()                                                         \
    {                                                                         \
        _Pragma("unroll")                                                     \
        for (int c = 0; c < 4; ++c) {                                         \
            uintx4 pk;                                                        \
            pk[0] = cvtpk(ra[2 * c][0], ra[2 * c][1]);                        \
            pk[1] = cvtpk(ra[2 * c][2], ra[2 * c][3]);                        \
            pk[2] = cvtpk(ra[2 * c + 1][0], ra[2 * c + 1][1]);                \
            pk[3] = cvtpk(ra[2 * c + 1][2], ra[2 * c + 1][3]);                \
            *(uintx4*)(&As[w * 32 + c * 8 + arow][aslot * 8]) = pk;           \
        }                                                                     \
    }

    // prologue: tile 0
    PROJ_STAGEB(0, 0);
    PROJ_LOADA(0);
    PROJ_WRITEA();
    __syncthreads();   // implicit vmcnt/lgkm drain: tile 0 resident

    for (int t = 0; t < 16; ++t) {
        const int cur = t & 1;
        if (t < 15) {
            PROJ_LOADA((t + 1) * 64);             // A loads issued early (T14)
            PROJ_STAGEB((t + 1) * 64, cur ^ 1);   // B DMA for next tile
        }

#pragma unroll
        for (int ks = 0; ks < 2; ++ks) {
            const int sw = ks ? sw1 : sw0;
            short8 af[4], bf[4];
#pragma unroll
            for (int i = 0; i < 4; ++i)
                af[i] = *(const short8*)(&As[wr + i * 16 + l15][0] + sw);
#pragma unroll
            for (int j = 0; j < 4; ++j)
                bf[j] = *(const short8*)(&Bs[cur][wc + j * 16 + l15][0] + sw);
#pragma unroll
            for (int i = 0; i < 4; ++i)
#pragma unroll
                for (int j = 0; j < 4; ++j)
                    acc[i][j] = __builtin_amdgcn_mfma_f32_16x16x32_bf16(
                        af[i], bf[j], acc[i][j], 0, 0, 0);
        }

        if (t < 15) {
            __syncthreads();   // As reads done everywhere; B DMA + A loads landed
            PROJ_WRITEA();     // overwrite As with tile t+1
            __syncthreads();   // As writes visible to all waves
        }
    }
#undef PROJ_STAGEB
#undef PROJ_LOADA
#undef PROJ_WRITEA

    // epilogue
#pragma unroll
    for (int j = 0; j < 4; ++j) {
        const int c = nb + wc + j * 16 + l15;
        const float bx = bias[c];
        const int hh = c >> 6, d = c & 63;
#pragma unroll
        for (int i = 0; i < 4; ++i) {
            if (z < 2) {   // heads [n][h][t][d]
#pragma unroll
                for (int r = 0; r < 4; ++r) {
                    const int m = mb + wr + i * 16 + quad * 4 + r;
                    const int nn = m >> 11, tt = m & 2047;
                    Y[(((size_t)(nn * HEADS + hh)) * T_S + tt) * DK + d] =
                        f2bf(acc[i][j][r] + bx);
                }
            } else {       // V transposed [n][h][d][t]
                const int m0 = mb + wr + i * 16 + quad * 4;
                const int nn = m0 >> 11, t0 = m0 & 2047;
                ushort4 o;
                o.x = f2bf(acc[i][j][0] + bx);
                o.y = f2bf(acc[i][j][1] + bx);
                o.z = f2bf(acc[i][j][2] + bx);
                o.w = f2bf(acc[i][j][3] + bx);
                *(ushort4*)(Y + (((size_t)(nn * HEADS + hh)) * DK + d) * T_S + t0) = o;
            }
        }
    }
}

// ---------------------------------------------------------------------------
// MFMA GEMM (bf16 A): output projection only (r7 version, measured < 81 us
// in-context).  Tile 128x128, BK=64, double-buffered 2-phase, XOR-swizzled
// LDS (pre-swizzled DMA source).  EPI2 = fp32 row-major [m][1024].
// ---------------------------------------------------------------------------
template <int EPI>
__global__ __launch_bounds__(256) void gemm_mfma(
    const ubf16* __restrict__ X, const ubf16* __restrict__ Wt,
    const float* __restrict__ bias, void* __restrict__ Yv)
{
    __shared__ ubf16 As[2][128][64];
    __shared__ ubf16 Bs[2][128][64];

    const int tid = threadIdx.x;
    const int mb = blockIdx.x * 128, nb = blockIdx.y * 128;
    const int w = tid >> 6, lid = tid & 63, quad = lid >> 4, l15 = lid & 15;
    const int wr = (w >> 1) * 64, wc = (w & 1) * 64;

    const int srow = lid >> 3;
    const int sch  = (lid & 7) ^ srow;
    const ubf16* gA = X  + (size_t)(mb + w * 32 + srow) * 1024 + sch * 8;
    const ubf16* gB = Wt + (size_t)(nb + w * 32 + srow) * 1024 + sch * 8;

    const int m7 = l15 & 7;
    const int sw0 = ((0 + quad) ^ m7) * 8;
    const int sw1 = ((4 + quad) ^ m7) * 8;

    floatx4 acc[4][4] = {};

#define GEMM_STAGE(KB, BUF)                                                  \
    {                                                                        \
        _Pragma("unroll")                                                    \
        for (int c = 0; c < 4; ++c) {                                        \
            async_copy16(gA + (size_t)(c * 8) * 1024 + (KB),                 \
                         &As[BUF][w * 32 + c * 8][0]);                       \
            async_copy16(gB + (size_t)(c * 8) * 1024 + (KB),                 \
                         &Bs[BUF][w * 32 + c * 8][0]);                       \
        }                                                                    \
    }

    GEMM_STAGE(0, 0);
    __syncthreads();

    for (int t = 0; t < 16; ++t) {
        const int cur = t & 1;
        if (t < 15) GEMM_STAGE((t + 1) * 64, cur ^ 1);

#pragma unroll
        for (int ks = 0; ks < 2; ++ks) {
            const int sw = ks ? sw1 : sw0;
            short8 af[4], bf[4];
#pragma unroll
            for (int i = 0; i < 4; ++i)
                af[i] = *(const short8*)(&As[cur][wr + i * 16 + l15][0] + sw);
#pragma unroll
            for (int j = 0; j < 4; ++j)
                bf[j] = *(const short8*)(&Bs[cur][wc + j * 16 + l15][0] + sw);
#pragma unroll
            for (int i = 0; i < 4; ++i)
#pragma unroll
                for (int j = 0; j < 4; ++j)
                    acc[i][j] = __builtin_amdgcn_mfma_f32_16x16x32_bf16(
                        af[i], bf[j], acc[i][j], 0, 0, 0);
        }
        __syncthreads();
    }
#undef GEMM_STAGE

#pragma unroll
    for (int j = 0; j < 4; ++j) {
        const int c = nb + wc + j * 16 + l15;
        const float bx = bias[c];
#pragma unroll
        for (int i = 0; i < 4; ++i) {
            float* Y = (float*)Yv;
#pragma unroll
            for (int r = 0; r < 4; ++r) {
                const int m = mb + wr + i * 16 + quad * 4 + r;
                Y[(size_t)m * DM + c] = acc[i][j][r] + bx;
            }
        }
    }
}

// ---------------------------------------------------------------------------
// Flash attention — BYTE-IDENTICAL to r3/r7/r8/r9 (measured 81.3-82.6 us).
// 32x32x16 MFMA, swapped operands, in-register P, LDS double-buffered K/V
// via global_load_lds, XOR-swizzled.  Causal balance: block bx does q-tile
// (15-bx) then bx; grid (8, HEADS, N_B).
// ---------------------------------------------------------------------------
__global__ __launch_bounds__(256, 4) void attn_mfma(
    const ubf16* __restrict__ Qh, const ubf16* __restrict__ Kh,
    const ubf16* __restrict__ Vt, const int* __restrict__ pm,
    ubf16* __restrict__ A)
{
    __shared__ ubf16 Ks[2][64 * 64];   // 8 KiB x2
    __shared__ ubf16 Vs[2][64 * 64];   // 8 KiB x2

    const int tid = threadIdx.x;
    const int w = tid >> 6, lid = tid & 63;
    const int l31 = lid & 31, hi = lid >> 5;
    const int bx = (int)blockIdx.x;                 // 0..7
    const int h = blockIdx.y, n = blockIdx.z;
    const size_t qkbase = ((size_t)(n * HEADS + h)) * T_S * DK;
    const size_t vbase  = ((size_t)(n * HEADS + h)) * DK * T_S;
    const int* pmn = pm + (size_t)n * T_S;

    const int srow = lid >> 3;                    // + c*8
    const int sch  = (lid & 7) ^ (srow & 7);      // pre-inverse-swizzled chunk

    int sw[4];
#pragma unroll
    for (int j = 0; j < 4; ++j) sw[j] = (((hi + 2 * j) ^ (l31 & 7)) * 8);

    for (int pass = 0; pass < 2; ++pass) {
        const int qt = pass == 0 ? (15 - bx) : bx;   // big pass first
        const int qb = qt * 128 + w * 32;            // this wave's q base
        const int qrow = qb + l31;                   // this lane's q

        short8 qf[4];
        {
            const ubf16* qp = Qh + qkbase + (size_t)qrow * DK + hi * 8;
#pragma unroll
            for (int dk = 0; dk < 4; ++dk)
                qf[dk] = *(const short8*)(qp + dk * 16);
        }

        const int ktm = 2 * qt + 1;            // block-uniform last tile

        {
            const int c0 = 2 * w;
#pragma unroll
            for (int cc = 0; cc < 2; ++cc) {
                const int c = c0 + cc;
                const int row = c * 8 + srow;
                async_copy16(Kh + qkbase + (size_t)row * DK + sch * 8, &Ks[0][c * 512]);
                async_copy16(Vt + vbase + (size_t)row * T_S + sch * 8, &Vs[0][c * 512]);
            }
        }
        __syncthreads();   // implicit vmcnt(0): tile 0 resident

        floatx16 o0 = {}, o1 = {};   // O^T: d = dc*32+(r&3)+8*(r>>2)+4*hi, q=l31
        float lsum = 0.f;

        for (int kt = 0; kt <= ktm; ++kt) {
            const int cur = kt & 1;
            const int kb = kt * 64;

            if (kt < ktm) {
                const int kb2 = kb + 64;
                const int c0 = 2 * w;
#pragma unroll
                for (int cc = 0; cc < 2; ++cc) {
                    const int c = c0 + cc;
                    const int row = c * 8 + srow;
                    async_copy16(Kh + qkbase + (size_t)(kb2 + row) * DK + sch * 8,
                                 &Ks[cur ^ 1][c * 512]);
                    async_copy16(Vt + vbase + (size_t)row * T_S + kb2 + sch * 8,
                                 &Vs[cur ^ 1][c * 512]);
                }
            }

            if (kb <= qb + 31) {   // wave-uniform: tile has visible keys
                const unsigned long long pmask = __ballot(pmn[kb + lid] != 0);
                const ubf16* Kr0 = &Ks[cur][l31 * 64];
                const ubf16* Kr1 = Kr0 + 32 * 64;
                const ubf16* Vr0 = &Vs[cur][l31 * 64];
                const ubf16* Vr1 = Vr0 + 32 * 64;
                const int qrel = qrow - kb;

                // ---------- half A: keys kb .. kb+31 ----------
                {
                    floatx16 s = {};
#pragma unroll
                    for (int dk = 0; dk < 4; ++dk) {
                        short8 kf = *(const short8*)(Kr0 + sw[dk]);
                        s = __builtin_amdgcn_mfma_f32_32x32x16_bf16(kf, qf[dk], s, 0, 0, 0);
                    }
                    float p[16];
                    const bool full = (kb + 31 <= qb) &&
                                      ((unsigned)pmask == 0xffffffffu);
                    if (full) {
#pragma unroll
                        for (int r = 0; r < 16; ++r) {
                            p[r] = __expf(s[r] * 0.125f);
                            lsum += p[r];
                        }
                    } else {
#pragma unroll
                        for (int r = 0; r < 16; ++r) {
                            const int k0 = (r & 3) + 8 * (r >> 2) + 4 * hi;
                            const bool ok = (((pmask >> k0) & 1ull) != 0) && (k0 <= qrel);
                            p[r] = ok ? __expf(s[r] * 0.125f) : 0.f;
                            lsum += p[r];
                        }
                    }
                    unsigned wa[8];
#pragma unroll
                    for (int t = 0; t < 8; ++t) wa[t] = cvtpk(p[2 * t], p[2 * t + 1]);
                    pswap(wa[0], wa[2]); pswap(wa[1], wa[3]);
                    pswap(wa[4], wa[6]); pswap(wa[5], wa[7]);
                    short8 pf0 = __builtin_bit_cast(short8, (uintx4){wa[0], wa[1], wa[2], wa[3]});
                    short8 pf1 = __builtin_bit_cast(short8, (uintx4){wa[4], wa[5], wa[6], wa[7]});
                    {
                        short8 vf0 = *(const short8*)(Vr0 + sw[0]);
                        short8 vf1 = *(const short8*)(Vr1 + sw[0]);
                        o0 = __builtin_amdgcn_mfma_f32_32x32x16_bf16(vf0, pf0, o0, 0, 0, 0);
                        o1 = __builtin_amdgcn_mfma_f32_32x32x16_bf16(vf1, pf0, o1, 0, 0, 0);
                        vf0 = *(const short8*)(Vr0 + sw[1]);
                        vf1 = *(const short8*)(Vr1 + sw[1]);
                        o0 = __builtin_amdgcn_mfma_f32_32x32x16_bf16(vf0, pf1, o0, 0, 0, 0);
                        o1 = __builtin_amdgcn_mfma_f32_32x32x16_bf16(vf1, pf1, o1, 0, 0, 0);
                    }
                }

                // ---------- half B: keys kb+32 .. kb+63 ----------
                if (kb + 32 <= qb + 31) {
                    floatx16 s = {};
#pragma unroll
                    for (int dk = 0; dk < 4; ++dk) {
                        short8 kf = *(const short8*)(Kr1 + sw[dk]);
                        s = __builtin_amdgcn_mfma_f32_32x32x16_bf16(kf, qf[dk], s, 0, 0, 0);
                    }
                    float p[16];
                    const bool full = (kb + 63 <= qb) &&
                                      ((unsigned)(pmask >> 32) == 0xffffffffu);
                    if (full) {
#pragma unroll
                        for (int r = 0; r < 16; ++r) {
                            p[r] = __expf(s[r] * 0.125f);
                            lsum += p[r];
                        }
                    } else {
#pragma unroll
                        for (int r = 0; r < 16; ++r) {
                            const int k1 = 32 + (r & 3) + 8 * (r >> 2) + 4 * hi;
                            const bool ok = (((pmask >> k1) & 1ull) != 0) && (k1 <= qrel);
                            p[r] = ok ? __expf(s[r] * 0.125f) : 0.f;
                            lsum += p[r];
                        }
                    }
                    unsigned wb[8];
#pragma unroll
                    for (int t = 0; t < 8; ++t) wb[t] = cvtpk(p[2 * t], p[2 * t + 1]);
                    pswap(wb[0], wb[2]); pswap(wb[1], wb[3]);
                    pswap(wb[4], wb[6]); pswap(wb[5], wb[7]);
                    short8 pf2 = __builtin_bit_cast(short8, (uintx4){wb[0], wb[1], wb[2], wb[3]});
                    short8 pf3 = __builtin_bit_cast(short8, (uintx4){wb[4], wb[5], wb[6], wb[7]});
                    {
                        short8 vf0 = *(const short8*)(Vr0 + sw[2]);
                        short8 vf1 = *(const short8*)(Vr1 + sw[2]);
                        o0 = __builtin_amdgcn_mfma_f32_32x32x16_bf16(vf0, pf2, o0, 0, 0, 0);
                        o1 = __builtin_amdgcn_mfma_f32_32x32x16_bf16(vf1, pf2, o1, 0, 0, 0);
                        vf0 = *(const short8*)(Vr0 + sw[3]);
                        vf1 = *(const short8*)(Vr1 + sw[3]);
                        o0 = __builtin_amdgcn_mfma_f32_32x32x16_bf16(vf0, pf3, o0, 0, 0, 0);
                        o1 = __builtin_amdgcn_mfma_f32_32x32x16_bf16(vf1, pf3, o1, 0, 0, 0);
                    }
                }
            }
            __syncthreads();   // cur reads done; next-tile DMA drained
        }

        // ---- normalize + store: A [n][t][h*64+d] bf16 ----
        lsum += __shfl_xor(lsum, 32);
        const float inv = lsum > 0.f ? 1.0f / lsum : 0.f;

        ubf16* ap = A + ((size_t)n * T_S + qrow) * DM + h * DK;
#pragma unroll
        for (int g = 0; g < 4; ++g) {
            uint2 uv;
            uv.x = cvtpk(o0[4 * g + 0] * inv, o0[4 * g + 1] * inv);
            uv.y = cvtpk(o0[4 * g + 2] * inv, o0[4 * g + 3] * inv);
            *(uint2*)(ap + 8 * g + 4 * hi) = uv;
            uv.x = cvtpk(o1[4 * g + 0] * inv, o1[4 * g + 1] * inv);
            uv.y = cvtpk(o1[4 * g + 2] * inv, o1[4 * g + 3] * inv);
            *(uint2*)(ap + 32 + 8 * g + 4 * hi) = uv;
        }
    }
}

// ---------------------------------------------------------------------------
extern "C" void kernel_launch(void* const* d_in, const int* in_sizes, int n_in,
                              void* d_out, int out_size, void* d_ws, size_t ws_size,
                              hipStream_t stream)
{
    const float* q  = (const float*)d_in[0];
    const float* k  = (const float*)d_in[1];
    const float* v  = (const float*)d_in[2];
    const int*   pm = (const int*)d_in[3];
    const float* Wq = (const float*)d_in[4];
    const float* bq = (const float*)d_in[5];
    const float* Wk = (const float*)d_in[6];
    const float* bk = (const float*)d_in[7];
    const float* Wv = (const float*)d_in[8];
    const float* bv = (const float*)d_in[9];
    const float* Wo = (const float*)d_in[10];
    const float* bo = (const float*)d_in[11];
    float* out = (float*)d_out;

    const size_t WT_E = (size_t)1024 * 1024;      // per-weight bf16 elems (2 MiB)
    const size_t HB_E = (size_t)8192 * 1024;      // batched per-tensor elems (16 MiB)
    const size_t PB_E = (size_t)2048 * 1024;      // per-batch elems (4 MiB)

    ubf16* WtQ = (ubf16*)d_ws;
    ubf16* WtK = WtQ + WT_E;
    ubf16* WtV = WtK + WT_E;
    ubf16* WtO = WtV + WT_E;
    ubf16* base = WtO + WT_E;

    dim3 blk(256);
    dim3 gtr(16, 16);
    wtrans<<<gtr, blk, 0, stream>>>(Wq, WtQ);
    wtrans<<<gtr, blk, 0, stream>>>(Wk, WtK);
    wtrans<<<gtr, blk, 0, stream>>>(Wv, WtV);
    wtrans<<<gtr, blk, 0, stream>>>(Wo, WtO);

    const size_t need_batched = (4 * WT_E + 4 * HB_E) * sizeof(ubf16);  // 72 MiB
    if (ws_size >= need_batched) {
        ubf16* Qh = base;
        ubf16* Kh = Qh + HB_E;
        ubf16* Vt = Kh + HB_E;
        ubf16* Aw = Vt + HB_E;
        dim3 gp(64, 8, 3);           // fused Q/K/V projections (1536 blocks)
        proj_mfma<<<gp, blk, 0, stream>>>(q, k, v, WtQ, WtK, WtV,
                                          bq, bk, bv, Qh, Kh, Vt);
        dim3 ga(8, HEADS, N_B);      // paired q-tiles (34 key-tiles per block)
        attn_mfma<<<ga, blk, 0, stream>>>(Qh, Kh, Vt, pm, Aw);
        dim3 gg(64, 8);
        gemm_mfma<2><<<gg, blk, 0, stream>>>(Aw, WtO, bo, out);
    } else {
        // per-batch fallback (24 MiB workspace)
        ubf16* Qh = base;
        ubf16* Kh = Qh + PB_E;
        ubf16* Vt = Kh + PB_E;
        ubf16* Aw = Vt + PB_E;
        dim3 gp(16, 8, 3);
        dim3 ga(8, HEADS, 1);
        dim3 gg(16, 8);
        for (int n = 0; n < N_B; ++n) {
            const size_t xoff = (size_t)n * T_S * DM;
            proj_mfma<<<gp, blk, 0, stream>>>(q + xoff, k + xoff, v + xoff,
                                              WtQ, WtK, WtV, bq, bk, bv,
                                              Qh, Kh, Vt);
            attn_mfma<<<ga, blk, 0, stream>>>(Qh, Kh, Vt, pm + n * T_S, Aw);
            gemm_mfma<2><<<gg, blk, 0, stream>>>(Aw, WtO, bo, out + xoff);
        }
    }
}

// Round 12
// 348.809 us; speedup vs baseline: 1.1401x; 1.0085x over previous
//
#include <hip/hip_runtime.h>
#include <hip/hip_bf16.h>

// Problem constants (fixed by the reference)
#define N_B   4
#define T_S   2048
#define DM    1024
#define HEADS 16
#define DK    64

// attention scale folded into Q projection: 1/sqrt(DK) * log2(e)
#define QSCALE 0.18033688011112042f

typedef unsigned short ubf16;  // raw bf16 bits
typedef __attribute__((ext_vector_type(8))) short short8;     // MFMA A/B frag (8 bf16)
typedef __attribute__((ext_vector_type(4))) float floatx4;    // 16x16 MFMA C/D frag
typedef __attribute__((ext_vector_type(16))) float floatx16;  // 32x32 MFMA C/D frag
typedef __attribute__((ext_vector_type(4))) unsigned uintx4;

__device__ __forceinline__ unsigned short f2bf(float f) {
    unsigned u = __float_as_uint(f);
    u += 0x7fff + ((u >> 16) & 1);   // round-to-nearest-even
    return (unsigned short)(u >> 16);
}
// packed f32x2 -> bf16x2 via HW cvt_pk (r3/r5/r7-proven in P-path and staging)
__device__ __forceinline__ unsigned cvtpk(float a, float b) {
    unsigned r;
    asm("v_cvt_pk_bf16_f32 %0, %1, %2" : "=v"(r) : "v"(a), "v"(b));
    return r;
}
// swap a.hi32lanes <-> b.lo32lanes (gfx950)
__device__ __forceinline__ void pswap(unsigned& a, unsigned& b) {
    asm volatile("v_permlane32_swap_b32 %0, %1" : "+v"(a), "+v"(b));
}
// 2^x as a single schedulable v_exp_f32 (scale pre-folded into Q)
__device__ __forceinline__ float exp2fast(float x) {
#if __has_builtin(__builtin_amdgcn_exp2f)
    return __builtin_amdgcn_exp2f(x);
#else
    return exp2f(x);
#endif
}

// async global->LDS DMA, 16 B per lane; LDS dest = wave-uniform base + lane*16
__device__ __forceinline__ void async_copy16(const ubf16* g, ubf16* l) {
    __builtin_amdgcn_global_load_lds(
        (const __attribute__((address_space(1))) void*)g,
        (__attribute__((address_space(3))) void*)l, 16, 0, 0);
}

// ---------------------------------------------------------------------------
// Weight transpose+convert+scale: W fp32 [k][n] -> Wt bf16 [n][k] * scale.
// ---------------------------------------------------------------------------
__global__ __launch_bounds__(256) void wtrans(
    const float* __restrict__ W, ubf16* __restrict__ Wt, float scale)
{
    __shared__ ubf16 T[64][72];
    const int tid = threadIdx.x;
    const int kb = blockIdx.x * 64, nb = blockIdx.y * 64;
    const int r = tid >> 2, cc = (tid & 3) * 16;
    const float* p = W + (size_t)(kb + r) * 1024 + nb + cc;
#pragma unroll
    for (int t = 0; t < 16; t += 4) {
        float4 x = *(const float4*)(p + t);
        T[r][cc + t + 0] = f2bf(x.x * scale);
        T[r][cc + t + 1] = f2bf(x.y * scale);
        T[r][cc + t + 2] = f2bf(x.z * scale);
        T[r][cc + t + 3] = f2bf(x.w * scale);
    }
    __syncthreads();
    ubf16 buf[16];
#pragma unroll
    for (int t = 0; t < 16; ++t) buf[t] = T[cc + t][r];   // transpose read
    ubf16* op = Wt + (size_t)(nb + r) * 1024 + kb + cc;
    *(uint4*)op       = *(uint4*)buf;
    *(uint4*)(op + 8) = *(uint4*)(buf + 8);
}

// ---------------------------------------------------------------------------
// Fused Q/K/V projection GEMM (r7/r11 version, measured 123-125 us): grid z
// picks (X, Wt, bias, Y, epilogue).  A = fp32 X reg-staged; B = bf16 Wt via
// global_load_lds.  Tile 128x128, BK=64, 4 waves; As single-buffered
// (48 KiB -> 3 blocks/CU).  XOR-swizzled LDS.  WQ is pre-scaled by QSCALE
// (wtrans); bQ gets the matching bscale here.
// z<2 -> heads [n][h][t][d]; z==2 -> V-transposed [n][h][d][t].
// ---------------------------------------------------------------------------
__global__ __launch_bounds__(256) void proj_mfma(
    const float* __restrict__ Xq, const float* __restrict__ Xk,
    const float* __restrict__ Xv,
    const ubf16* __restrict__ WQ, const ubf16* __restrict__ WK,
    const ubf16* __restrict__ WV,
    const float* __restrict__ bQ, const float* __restrict__ bK,
    const float* __restrict__ bV,
    ubf16* __restrict__ YQ, ubf16* __restrict__ YK, ubf16* __restrict__ YV)
{
    __shared__ ubf16 As[128][64];     // 16 KiB, single buffer
    __shared__ ubf16 Bs[2][128][64];  // 16 KiB per buf

    const int z = blockIdx.z;
    const float* X    = z == 0 ? Xq : (z == 1 ? Xk : Xv);
    const ubf16* Wt   = z == 0 ? WQ : (z == 1 ? WK : WV);
    const float* bias = z == 0 ? bQ : (z == 1 ? bK : bV);
    ubf16* Y          = z == 0 ? YQ : (z == 1 ? YK : YV);
    const float bscale = (z == 0) ? QSCALE : 1.0f;   // WQ pre-scaled in wtrans

    const int tid = threadIdx.x;
    const int mb = blockIdx.x * 128, nb = blockIdx.y * 128;
    const int w = tid >> 6, lid = tid & 63, quad = lid >> 4, l15 = lid & 15;
    const int wr = (w >> 1) * 64, wc = (w & 1) * 64;

    // B DMA pattern: row = c*8 + (lid>>3), source chunk pre-inverse-swizzled
    const int srow = lid >> 3;                 // 0..7
    const int sch  = (lid & 7) ^ srow;
    const ubf16* gB = Wt + (size_t)(nb + w * 32 + srow) * 1024 + sch * 8;

    // A reg-staging pattern: lane owns row c*8+arow, fp32 chunk ach (8 floats)
    const int arow = lid >> 3, ach = lid & 7;
    const int aslot = ach ^ arow;              // swizzled LDS chunk for write
    const float* gA = X + (size_t)(mb + w * 32 + arow) * 1024 + ach * 8;

    // frag-read swizzled chunk offsets: ((ks*4+quad) ^ (row&7)) * 8
    const int m7 = l15 & 7;
    const int sw0 = ((0 + quad) ^ m7) * 8;     // ks = 0
    const int sw1 = ((4 + quad) ^ m7) * 8;     // ks = 1

    floatx4 acc[4][4] = {};
    float4 ra[8];

#define PROJ_STAGEB(KB, BUF)                                                  \
    {                                                                         \
        _Pragma("unroll")                                                     \
        for (int c = 0; c < 4; ++c)                                           \
            async_copy16(gB + (size_t)(c * 8) * 1024 + (KB),                  \
                         &Bs[BUF][w * 32 + c * 8][0]);                        \
    }
#define PROJ_LOADA(KB)                                                        \
    {                                                                         \
        _Pragma("unroll")                                                     \
        for (int c = 0; c < 4; ++c) {                                         \
            const float* p = gA + (size_t)(c * 8) * 1024 + (KB);              \
            ra[2 * c]     = *(const float4*)p;                                \
            ra[2 * c + 1] = *(const float4*)(p + 4);                          \
        }                                                                     \
    }
#define PROJ_WRITEA()                                                         \
    {                                                                         \
        _Pragma("unroll")                                                     \
        for (int c = 0; c < 4; ++c) {                                         \
            uintx4 pk;                                                        \
            pk[0] = cvtpk(ra[2 * c][0], ra[2 * c][1]);                        \
            pk[1] = cvtpk(ra[2 * c][2], ra[2 * c][3]);                        \
            pk[2] = cvtpk(ra[2 * c + 1][0], ra[2 * c + 1][1]);                \
            pk[3] = cvtpk(ra[2 * c + 1][2], ra[2 * c + 1][3]);                \
            *(uintx4*)(&As[w * 32 + c * 8 + arow][aslot * 8]) = pk;           \
        }                                                                     \
    }

    // prologue: tile 0
    PROJ_STAGEB(0, 0);
    PROJ_LOADA(0);
    PROJ_WRITEA();
    __syncthreads();   // implicit vmcnt/lgkm drain: tile 0 resident

    for (int t = 0; t < 16; ++t) {
        const int cur = t & 1;
        if (t < 15) {
            PROJ_LOADA((t + 1) * 64);             // A loads issued early (T14)
            PROJ_STAGEB((t + 1) * 64, cur ^ 1);   // B DMA for next tile
        }

#pragma unroll
        for (int ks = 0; ks < 2; ++ks) {
            const int sw = ks ? sw1 : sw0;
            short8 af[4], bf[4];
#pragma unroll
            for (int i = 0; i < 4; ++i)
                af[i] = *(const short8*)(&As[wr + i * 16 + l15][0] + sw);
#pragma unroll
            for (int j = 0; j < 4; ++j)
                bf[j] = *(const short8*)(&Bs[cur][wc + j * 16 + l15][0] + sw);
#pragma unroll
            for (int i = 0; i < 4; ++i)
#pragma unroll
                for (int j = 0; j < 4; ++j)
                    acc[i][j] = __builtin_amdgcn_mfma_f32_16x16x32_bf16(
                        af[i], bf[j], acc[i][j], 0, 0, 0);
        }

        if (t < 15) {
            __syncthreads();   // As reads done everywhere; B DMA + A loads landed
            PROJ_WRITEA();     // overwrite As with tile t+1
            __syncthreads();   // As writes visible to all waves
        }
    }
#undef PROJ_STAGEB
#undef PROJ_LOADA
#undef PROJ_WRITEA

    // epilogue
#pragma unroll
    for (int j = 0; j < 4; ++j) {
        const int c = nb + wc + j * 16 + l15;
        const float bx = bias[c] * bscale;
        const int hh = c >> 6, d = c & 63;
#pragma unroll
        for (int i = 0; i < 4; ++i) {
            if (z < 2) {   // heads [n][h][t][d]
#pragma unroll
                for (int r = 0; r < 4; ++r) {
                    const int m = mb + wr + i * 16 + quad * 4 + r;
                    const int nn = m >> 11, tt = m & 2047;
                    Y[(((size_t)(nn * HEADS + hh)) * T_S + tt) * DK + d] =
                        f2bf(acc[i][j][r] + bx);
                }
            } else {       // V transposed [n][h][d][t]
                const int m0 = mb + wr + i * 16 + quad * 4;
                const int nn = m0 >> 11, t0 = m0 & 2047;
                ushort4 o;
                o.x = f2bf(acc[i][j][0] + bx);
                o.y = f2bf(acc[i][j][1] + bx);
                o.z = f2bf(acc[i][j][2] + bx);
                o.w = f2bf(acc[i][j][3] + bx);
                *(ushort4*)(Y + (((size_t)(nn * HEADS + hh)) * DK + d) * T_S + t0) = o;
            }
        }
    }
}

// ---------------------------------------------------------------------------
// MFMA GEMM (bf16 A): output projection only (r7/r11 version, measured < 81
// us in-context).  Tile 128x128, BK=64, double-buffered 2-phase,
// XOR-swizzled LDS (pre-swizzled DMA source).  EPI2 = fp32 [m][1024].
// ---------------------------------------------------------------------------
template <int EPI>
__global__ __launch_bounds__(256) void gemm_mfma(
    const ubf16* __restrict__ X, const ubf16* __restrict__ Wt,
    const float* __restrict__ bias, void* __restrict__ Yv)
{
    __shared__ ubf16 As[2][128][64];
    __shared__ ubf16 Bs[2][128][64];

    const int tid = threadIdx.x;
    const int mb = blockIdx.x * 128, nb = blockIdx.y * 128;
    const int w = tid >> 6, lid = tid & 63, quad = lid >> 4, l15 = lid & 15;
    const int wr = (w >> 1) * 64, wc = (w & 1) * 64;

    const int srow = lid >> 3;
    const int sch  = (lid & 7) ^ srow;
    const ubf16* gA = X  + (size_t)(mb + w * 32 + srow) * 1024 + sch * 8;
    const ubf16* gB = Wt + (size_t)(nb + w * 32 + srow) * 1024 + sch * 8;

    const int m7 = l15 & 7;
    const int sw0 = ((0 + quad) ^ m7) * 8;
    const int sw1 = ((4 + quad) ^ m7) * 8;

    floatx4 acc[4][4] = {};

#define GEMM_STAGE(KB, BUF)                                                  \
    {                                                                        \
        _Pragma("unroll")                                                    \
        for (int c = 0; c < 4; ++c) {                                        \
            async_copy16(gA + (size_t)(c * 8) * 1024 + (KB),                 \
                         &As[BUF][w * 32 + c * 8][0]);                       \
            async_copy16(gB + (size_t)(c * 8) * 1024 + (KB),                 \
                         &Bs[BUF][w * 32 + c * 8][0]);                       \
        }                                                                    \
    }

    GEMM_STAGE(0, 0);
    __syncthreads();

    for (int t = 0; t < 16; ++t) {
        const int cur = t & 1;
        if (t < 15) GEMM_STAGE((t + 1) * 64, cur ^ 1);

#pragma unroll
        for (int ks = 0; ks < 2; ++ks) {
            const int sw = ks ? sw1 : sw0;
            short8 af[4], bf[4];
#pragma unroll
            for (int i = 0; i < 4; ++i)
                af[i] = *(const short8*)(&As[cur][wr + i * 16 + l15][0] + sw);
#pragma unroll
            for (int j = 0; j < 4; ++j)
                bf[j] = *(const short8*)(&Bs[cur][wc + j * 16 + l15][0] + sw);
#pragma unroll
            for (int i = 0; i < 4; ++i)
#pragma unroll
                for (int j = 0; j < 4; ++j)
                    acc[i][j] = __builtin_amdgcn_mfma_f32_16x16x32_bf16(
                        af[i], bf[j], acc[i][j], 0, 0, 0);
        }
        __syncthreads();
    }
#undef GEMM_STAGE

#pragma unroll
    for (int j = 0; j < 4; ++j) {
        const int c = nb + wc + j * 16 + l15;
        const float bx = bias[c];
#pragma unroll
        for (int i = 0; i < 4; ++i) {
            float* Y = (float*)Yv;
#pragma unroll
            for (int r = 0; r < 4; ++r) {
                const int m = mb + wr + i * 16 + quad * 4 + r;
                Y[(size_t)m * DM + c] = acc[i][j][r] + bx;
            }
        }
    }
}

// ---------------------------------------------------------------------------
// Flash attention — r3/r7/r11 structure (measured 81.3-82.6 us) with ONE
// change: Q arrives pre-scaled by 0.125*log2(e) (folded into WQ/bQ), so
// softmax is exp2fast(s) — a single schedulable v_exp_f32 instead of
// v_mul+v_exp.  The wave-uniform `full` branch and per-element masked path
// are byte-identical to r3 (the r5/r6 regression was the per-lane divergent
// vis-mask branch, NOT the exp2 — kept out).
// Causal balance: block bx does q-tile (15-bx) then bx; grid (8, HEADS, N_B).
// ---------------------------------------------------------------------------
__global__ __launch_bounds__(256, 4) void attn_mfma(
    const ubf16* __restrict__ Qh, const ubf16* __restrict__ Kh,
    const ubf16* __restrict__ Vt, const int* __restrict__ pm,
    ubf16* __restrict__ A)
{
    __shared__ ubf16 Ks[2][64 * 64];   // 8 KiB x2
    __shared__ ubf16 Vs[2][64 * 64];   // 8 KiB x2

    const int tid = threadIdx.x;
    const int w = tid >> 6, lid = tid & 63;
    const int l31 = lid & 31, hi = lid >> 5;
    const int bx = (int)blockIdx.x;                 // 0..7
    const int h = blockIdx.y, n = blockIdx.z;
    const size_t qkbase = ((size_t)(n * HEADS + h)) * T_S * DK;
    const size_t vbase  = ((size_t)(n * HEADS + h)) * DK * T_S;
    const int* pmn = pm + (size_t)n * T_S;

    const int srow = lid >> 3;                    // + c*8
    const int sch  = (lid & 7) ^ (srow & 7);      // pre-inverse-swizzled chunk

    int sw[4];
#pragma unroll
    for (int j = 0; j < 4; ++j) sw[j] = (((hi + 2 * j) ^ (l31 & 7)) * 8);

    for (int pass = 0; pass < 2; ++pass) {
        const int qt = pass == 0 ? (15 - bx) : bx;   // big pass first
        const int qb = qt * 128 + w * 32;            // this wave's q base
        const int qrow = qb + l31;                   // this lane's q

        short8 qf[4];
        {
            const ubf16* qp = Qh + qkbase + (size_t)qrow * DK + hi * 8;
#pragma unroll
            for (int dk = 0; dk < 4; ++dk)
                qf[dk] = *(const short8*)(qp + dk * 16);
        }

        const int ktm = 2 * qt + 1;            // block-uniform last tile

        {
            const int c0 = 2 * w;
#pragma unroll
            for (int cc = 0; cc < 2; ++cc) {
                const int c = c0 + cc;
                const int row = c * 8 + srow;
                async_copy16(Kh + qkbase + (size_t)row * DK + sch * 8, &Ks[0][c * 512]);
                async_copy16(Vt + vbase + (size_t)row * T_S + sch * 8, &Vs[0][c * 512]);
            }
        }
        __syncthreads();   // implicit vmcnt(0): tile 0 resident

        floatx16 o0 = {}, o1 = {};   // O^T: d = dc*32+(r&3)+8*(r>>2)+4*hi, q=l31
        float lsum = 0.f;

        for (int kt = 0; kt <= ktm; ++kt) {
            const int cur = kt & 1;
            const int kb = kt * 64;

            if (kt < ktm) {
                const int kb2 = kb + 64;
                const int c0 = 2 * w;
#pragma unroll
                for (int cc = 0; cc < 2; ++cc) {
                    const int c = c0 + cc;
                    const int row = c * 8 + srow;
                    async_copy16(Kh + qkbase + (size_t)(kb2 + row) * DK + sch * 8,
                                 &Ks[cur ^ 1][c * 512]);
                    async_copy16(Vt + vbase + (size_t)row * T_S + kb2 + sch * 8,
                                 &Vs[cur ^ 1][c * 512]);
                }
            }

            if (kb <= qb + 31) {   // wave-uniform: tile has visible keys
                const unsigned long long pmask = __ballot(pmn[kb + lid] != 0);
                const ubf16* Kr0 = &Ks[cur][l31 * 64];
                const ubf16* Kr1 = Kr0 + 32 * 64;
                const ubf16* Vr0 = &Vs[cur][l31 * 64];
                const ubf16* Vr1 = Vr0 + 32 * 64;
                const int qrel = qrow - kb;

                // ---------- half A: keys kb .. kb+31 ----------
                {
                    floatx16 s = {};
#pragma unroll
                    for (int dk = 0; dk < 4; ++dk) {
                        short8 kf = *(const short8*)(Kr0 + sw[dk]);
                        s = __builtin_amdgcn_mfma_f32_32x32x16_bf16(kf, qf[dk], s, 0, 0, 0);
                    }
                    float p[16];
                    const bool full = (kb + 31 <= qb) &&
                                      ((unsigned)pmask == 0xffffffffu);
                    if (full) {
#pragma unroll
                        for (int r = 0; r < 16; ++r) {
                            p[r] = exp2fast(s[r]);
                            lsum += p[r];
                        }
                    } else {
#pragma unroll
                        for (int r = 0; r < 16; ++r) {
                            const int k0 = (r & 3) + 8 * (r >> 2) + 4 * hi;
                            const bool ok = (((pmask >> k0) & 1ull) != 0) && (k0 <= qrel);
                            p[r] = ok ? exp2fast(s[r]) : 0.f;
                            lsum += p[r];
                        }
                    }
                    unsigned wa[8];
#pragma unroll
                    for (int t = 0; t < 8; ++t) wa[t] = cvtpk(p[2 * t], p[2 * t + 1]);
                    pswap(wa[0], wa[2]); pswap(wa[1], wa[3]);
                    pswap(wa[4], wa[6]); pswap(wa[5], wa[7]);
                    short8 pf0 = __builtin_bit_cast(short8, (uintx4){wa[0], wa[1], wa[2], wa[3]});
                    short8 pf1 = __builtin_bit_cast(short8, (uintx4){wa[4], wa[5], wa[6], wa[7]});
                    {
                        short8 vf0 = *(const short8*)(Vr0 + sw[0]);
                        short8 vf1 = *(const short8*)(Vr1 + sw[0]);
                        o0 = __builtin_amdgcn_mfma_f32_32x32x16_bf16(vf0, pf0, o0, 0, 0, 0);
                        o1 = __builtin_amdgcn_mfma_f32_32x32x16_bf16(vf1, pf0, o1, 0, 0, 0);
                        vf0 = *(const short8*)(Vr0 + sw[1]);
                        vf1 = *(const short8*)(Vr1 + sw[1]);
                        o0 = __builtin_amdgcn_mfma_f32_32x32x16_bf16(vf0, pf1, o0, 0, 0, 0);
                        o1 = __builtin_amdgcn_mfma_f32_32x32x16_bf16(vf1, pf1, o1, 0, 0, 0);
                    }
                }

                // ---------- half B: keys kb+32 .. kb+63 ----------
                if (kb + 32 <= qb + 31) {
                    floatx16 s = {};
#pragma unroll
                    for (int dk = 0; dk < 4; ++dk) {
                        short8 kf = *(const short8*)(Kr1 + sw[dk]);
                        s = __builtin_amdgcn_mfma_f32_32x32x16_bf16(kf, qf[dk], s, 0, 0, 0);
                    }
                    float p[16];
                    const bool full = (kb + 63 <= qb) &&
                                      ((unsigned)(pmask >> 32) == 0xffffffffu);
                    if (full) {
#pragma unroll
                        for (int r = 0; r < 16; ++r) {
                            p[r] = exp2fast(s[r]);
                            lsum += p[r];
                        }
                    } else {
#pragma unroll
                        for (int r = 0; r < 16; ++r) {
                            const int k1 = 32 + (r & 3) + 8 * (r >> 2) + 4 * hi;
                            const bool ok = (((pmask >> k1) & 1ull) != 0) && (k1 <= qrel);
                            p[r] = ok ? exp2fast(s[r]) : 0.f;
                            lsum += p[r];
                        }
                    }
                    unsigned wb[8];
#pragma unroll
                    for (int t = 0; t < 8; ++t) wb[t] = cvtpk(p[2 * t], p[2 * t + 1]);
                    pswap(wb[0], wb[2]); pswap(wb[1], wb[3]);
                    pswap(wb[4], wb[6]); pswap(wb[5], wb[7]);
                    short8 pf2 = __builtin_bit_cast(short8, (uintx4){wb[0], wb[1], wb[2], wb[3]});
                    short8 pf3 = __builtin_bit_cast(short8, (uintx4){wb[4], wb[5], wb[6], wb[7]});
                    {
                        short8 vf0 = *(const short8*)(Vr0 + sw[2]);
                        short8 vf1 = *(const short8*)(Vr1 + sw[2]);
                        o0 = __builtin_amdgcn_mfma_f32_32x32x16_bf16(vf0, pf2, o0, 0, 0, 0);
                        o1 = __builtin_amdgcn_mfma_f32_32x32x16_bf16(vf1, pf2, o1, 0, 0, 0);
                        vf0 = *(const short8*)(Vr0 + sw[3]);
                        vf1 = *(const short8*)(Vr1 + sw[3]);
                        o0 = __builtin_amdgcn_mfma_f32_32x32x16_bf16(vf0, pf3, o0, 0, 0, 0);
                        o1 = __builtin_amdgcn_mfma_f32_32x32x16_bf16(vf1, pf3, o1, 0, 0, 0);
                    }
                }
            }
            __syncthreads();   // cur reads done; next-tile DMA drained
        }

        // ---- normalize + store: A [n][t][h*64+d] bf16 ----
        lsum += __shfl_xor(lsum, 32);
        const float inv = lsum > 0.f ? 1.0f / lsum : 0.f;

        ubf16* ap = A + ((size_t)n * T_S + qrow) * DM + h * DK;
#pragma unroll
        for (int g = 0; g < 4; ++g) {
            uint2 uv;
            uv.x = cvtpk(o0[4 * g + 0] * inv, o0[4 * g + 1] * inv);
            uv.y = cvtpk(o0[4 * g + 2] * inv, o0[4 * g + 3] * inv);
            *(uint2*)(ap + 8 * g + 4 * hi) = uv;
            uv.x = cvtpk(o1[4 * g + 0] * inv, o1[4 * g + 1] * inv);
            uv.y = cvtpk(o1[4 * g + 2] * inv, o1[4 * g + 3] * inv);
            *(uint2*)(ap + 32 + 8 * g + 4 * hi) = uv;
        }
    }
}

// ---------------------------------------------------------------------------
extern "C" void kernel_launch(void* const* d_in, const int* in_sizes, int n_in,
                              void* d_out, int out_size, void* d_ws, size_t ws_size,
                              hipStream_t stream)
{
    const float* q  = (const float*)d_in[0];
    const float* k  = (const float*)d_in[1];
    const float* v  = (const float*)d_in[2];
    const int*   pm = (const int*)d_in[3];
    const float* Wq = (const float*)d_in[4];
    const float* bq = (const float*)d_in[5];
    const float* Wk = (const float*)d_in[6];
    const float* bk = (const float*)d_in[7];
    const float* Wv = (const float*)d_in[8];
    const float* bv = (const float*)d_in[9];
    const float* Wo = (const float*)d_in[10];
    const float* bo = (const float*)d_in[11];
    float* out = (float*)d_out;

    const size_t WT_E = (size_t)1024 * 1024;      // per-weight bf16 elems (2 MiB)
    const size_t HB_E = (size_t)8192 * 1024;      // batched per-tensor elems (16 MiB)
    const size_t PB_E = (size_t)2048 * 1024;      // per-batch elems (4 MiB)

    ubf16* WtQ = (ubf16*)d_ws;
    ubf16* WtK = WtQ + WT_E;
    ubf16* WtV = WtK + WT_E;
    ubf16* WtO = WtV + WT_E;
    ubf16* base = WtO + WT_E;

    dim3 blk(256);
    dim3 gtr(16, 16);
    wtrans<<<gtr, blk, 0, stream>>>(Wq, WtQ, QSCALE);   // fold attn scale into Q
    wtrans<<<gtr, blk, 0, stream>>>(Wk, WtK, 1.0f);
    wtrans<<<gtr, blk, 0, stream>>>(Wv, WtV, 1.0f);
    wtrans<<<gtr, blk, 0, stream>>>(Wo, WtO, 1.0f);

    const size_t need_batched = (4 * WT_E + 4 * HB_E) * sizeof(ubf16);  // 72 MiB
    if (ws_size >= need_batched) {
        ubf16* Qh = base;
        ubf16* Kh = Qh + HB_E;
        ubf16* Vt = Kh + HB_E;
        ubf16* Aw = Vt + HB_E;
        dim3 gp(64, 8, 3);           // fused Q/K/V projections (1536 blocks)
        proj_mfma<<<gp, blk, 0, stream>>>(q, k, v, WtQ, WtK, WtV,
                                          bq, bk, bv, Qh, Kh, Vt);
        dim3 ga(8, HEADS, N_B);      // paired q-tiles (34 key-tiles per block)
        attn_mfma<<<ga, blk, 0, stream>>>(Qh, Kh, Vt, pm, Aw);
        dim3 gg(64, 8);
        gemm_mfma<2><<<gg, blk, 0, stream>>>(Aw, WtO, bo, out);
    } else {
        // per-batch fallback (24 MiB workspace)
        ubf16* Qh = base;
        ubf16* Kh = Qh + PB_E;
        ubf16* Vt = Kh + PB_E;
        ubf16* Aw = Vt + PB_E;
        dim3 gp(16, 8, 3);
        dim3 ga(8, HEADS, 1);
        dim3 gg(16, 8);
        for (int n = 0; n < N_B; ++n) {
            const size_t xoff = (size_t)n * T_S * DM;
            proj_mfma<<<gp, blk, 0, stream>>>(q + xoff, k + xoff, v + xoff,
                                              WtQ, WtK, WtV, bq, bk, bv,
                                              Qh, Kh, Vt);
            attn_mfma<<<ga, blk, 0, stream>>>(Qh, Kh, Vt, pm + n * T_S, Aw);
            gemm_mfma<2><<<gg, blk, 0, stream>>>(Aw, WtO, bo, out + xoff);
        }
    }
}